// Round 1
// baseline (49.165 us; speedup 1.0000x reference)
//
#include <hip/hip_runtime.h>
#include <hip/hip_bf16.h>

typedef short v8s __attribute__((ext_vector_type(8)));
typedef float v16f __attribute__((ext_vector_type(16)));

// float -> bf16 bits (RNE)
__device__ __forceinline__ short f2bf(float f) {
    unsigned u = __builtin_bit_cast(unsigned, f);
    u = u + 0x7FFFu + ((u >> 16) & 1u);
    return (short)(u >> 16);
}

// Symmetric contraction as one bf16 GEMM  (M=BC=262144) x (K=180) x (N=256)
//   A[m, k3*16+i] = x[m,i]*w3[m,k3]   (k3<11);  A[m,176+k2] = w2[m,k2]
//   B[k3*16+i, p*16+q] = U3[p,q,i,k3];  B[176+k2, p*16+q] = U2[p,q,k2]
// final[m] = sum_n D[m,n]*x[m,n>>4]*x[m,n&15] + w1[m]*(U1 . x[m])
__global__ __launch_bounds__(256, 1)
void symcon_kernel(const float* __restrict__ x, const float* __restrict__ y,
                   const float* __restrict__ U3, const float* __restrict__ U2,
                   const float* __restrict__ U1, const float* __restrict__ W3,
                   const float* __restrict__ W2, const float* __restrict__ W1,
                   float* __restrict__ out)
{
    // B fragments: [kt(12)][nt(8)][lane(64)][j(8)] bf16 = 96 KB
    __shared__ __align__(16) short Blds[12 * 8 * 64 * 8];
    // permuted x tile: x_re[r][(i&1)*8 + (i>>1)] = x[r][i]  (8 KB)
    __shared__ __align__(16) float x_re[128][16];
    // cross-wave reduction buffer (34 KB)
    __shared__ __align__(16) float Sbuf[128][68];

    const int tid = threadIdx.x;

    // ---------- one-time: U3/U2 -> bf16 B-fragments in LDS ----------
    {
        const int n  = tid;        // output column index n = p*16+q, 0..255
        const int nt = n >> 5;
        const int lb = n & 31;
        const float* u3p = U3 + n * 176;   // contiguous [i][k3] block (i*11+k3)
        for (int i = 0; i < 16; ++i) {
            const int lane = lb | ((i >> 3) << 5);
            const int j    = i & 7;
            short* dst = &Blds[(((0 * 8 + nt) * 64 + lane) << 3) + j]; // kt stride = 4096 shorts
            #pragma unroll
            for (int k3 = 0; k3 < 11; ++k3)
                dst[k3 * 4096] = f2bf(u3p[i * 11 + k3]);
        }
        // kt = 11 : U2 occupies k=0..3, rest zero
        const int base0 = ((11 * 8 + nt) * 64 + lb) << 3;
        const float* u2p = U2 + n * 4;
        #pragma unroll
        for (int j = 0; j < 4; ++j) Blds[base0 + j] = f2bf(u2p[j]);
        #pragma unroll
        for (int j = 4; j < 8; ++j) Blds[base0 + j] = 0;
        const int base1 = ((11 * 8 + nt) * 64 + (lb + 32)) << 3;
        #pragma unroll
        for (int j = 0; j < 8; ++j) Blds[base1 + j] = 0;
    }

    // U1 in x_re slot order
    float u1p[16];
    #pragma unroll
    for (int s = 0; s < 16; ++s) {
        const int s2 = (s < 8) ? s : (s - 8);
        const int i  = ((s2 >> 2) << 3) + ((s2 & 3) << 1) + ((s < 8) ? 0 : 1);
        u1p[s] = U1[i];
    }

    const int lane = tid & 63;
    const int wid  = tid >> 6;
    const int mw   = wid >> 1;      // M half of block tile
    const int nw   = wid & 1;       // N half
    const int col  = lane & 31;
    const int h    = lane >> 5;

    const int r0 = mw * 64 + col;   // local row, mr=0
    const int r1 = r0 + 32;         // local row, mr=1

    for (int it = 0; it < 8; ++it) {
        const int tile = (int)blockIdx.x + (it << 8);   // 2048 tiles, 1 node each
        __syncthreads();   // Sbuf/x_re of previous tile fully consumed

        // ---- stage permuted x tile ----
        {
            const int r = tid >> 1, hf = tid & 1;
            const float* xp = x + ((size_t)tile * 128 + r) * 16 + hf * 8;
            const float4 a = *reinterpret_cast<const float4*>(xp);
            const float4 b = *reinterpret_cast<const float4*>(xp + 4);
            const float4 ev = make_float4(a.x, a.z, b.x, b.z);   // even i
            const float4 od = make_float4(a.y, a.w, b.y, b.w);   // odd  i
            *reinterpret_cast<float4*>(&x_re[r][hf * 4])     = ev;
            *reinterpret_cast<float4*>(&x_re[r][8 + hf * 4]) = od;
        }

        // ---- species (argmax, first-max wins) ----
        int e = 0;
        {
            const float* yr = y + tile * 10;
            float best = yr[0];
            #pragma unroll
            for (int s2 = 1; s2 < 10; ++s2) { const float v = yr[s2]; if (v > best) { best = v; e = s2; } }
        }

        // ---- per-lane weights (channel c == local row) ----
        float w3a[11], w3b[11], w2a[4], w2b[4];
        #pragma unroll
        for (int k = 0; k < 11; ++k) {
            w3a[k] = W3[(e * 11 + k) * 128 + r0];
            w3b[k] = W3[(e * 11 + k) * 128 + r1];
        }
        #pragma unroll
        for (int k = 0; k < 4; ++k) {
            w2a[k] = W2[(e * 4 + k) * 128 + r0];
            w2b[k] = W2[(e * 4 + k) * 128 + r1];
        }
        __syncthreads();   // x_re ready

        // xsel quads: x[row][h*8 + j]  (even j / odd j)
        float xe0[4], xo0[4], xe1[4], xo1[4];
        {
            const float4 a = *reinterpret_cast<float4*>(&x_re[r0][h * 4]);
            const float4 b = *reinterpret_cast<float4*>(&x_re[r0][8 + h * 4]);
            const float4 c = *reinterpret_cast<float4*>(&x_re[r1][h * 4]);
            const float4 d = *reinterpret_cast<float4*>(&x_re[r1][8 + h * 4]);
            xe0[0]=a.x; xe0[1]=a.y; xe0[2]=a.z; xe0[3]=a.w;
            xo0[0]=b.x; xo0[1]=b.y; xo0[2]=b.z; xo0[3]=b.w;
            xe1[0]=c.x; xe1[1]=c.y; xe1[2]=c.z; xe1[3]=c.w;
            xo1[0]=d.x; xo1[1]=d.y; xo1[2]=d.z; xo1[3]=d.w;
        }

        v16f acc[8] = {};   // [mr*4 + ntl]

        // ---- K loop: 11 U3 steps + 1 U2 step ----
        #pragma unroll
        for (int kt = 0; kt < 12; ++kt) {
            v8s bf[4];
            #pragma unroll
            for (int ntl = 0; ntl < 4; ++ntl) {
                const int ntg = nw * 4 + ntl;
                bf[ntl] = *reinterpret_cast<const v8s*>(&Blds[((kt * 8 + ntg) * 64 + lane) << 3]);
            }
            v8s a0, a1;
            if (kt < 11) {
                const float wa = w3a[kt], wb = w3b[kt];
                #pragma unroll
                for (int j = 0; j < 8; ++j) {
                    const float xs0 = (j & 1) ? xo0[j >> 1] : xe0[j >> 1];
                    const float xs1 = (j & 1) ? xo1[j >> 1] : xe1[j >> 1];
                    a0[j] = f2bf(xs0 * wa);
                    a1[j] = f2bf(xs1 * wb);
                }
            } else {
                #pragma unroll
                for (int j = 0; j < 8; ++j) {
                    const float f0 = (j < 4 && h == 0) ? w2a[j & 3] : 0.f;
                    const float f1 = (j < 4 && h == 0) ? w2b[j & 3] : 0.f;
                    a0[j] = f2bf(f0);
                    a1[j] = f2bf(f1);
                }
            }
            #pragma unroll
            for (int ntl = 0; ntl < 4; ++ntl) {
                acc[ntl]     = __builtin_amdgcn_mfma_f32_32x32x16_bf16(a0, bf[ntl], acc[ntl],     0, 0, 0);
                acc[4 + ntl] = __builtin_amdgcn_mfma_f32_32x32x16_bf16(a1, bf[ntl], acc[4 + ntl], 0, 0, 0);
            }
        }

        // ---- epilogue: S[m] += sum_n D[m,n]*x[m,p]*x[m,q] (this wave's n-half) ----
        const int q     = col & 15;
        const int qslot = ((q & 1) << 3) | (q >> 1);
        const int c4    = col >> 4;
        #pragma unroll
        for (int mr = 0; mr < 2; ++mr) {
            const int rb = mw * 64 + mr * 32 + 4 * h;
            #pragma unroll
            for (int rg = 0; rg < 16; ++rg) {
                const int row = rb + (rg & 3) + ((rg >> 2) << 3);
                const float  xq  = x_re[row][qslot];
                const float4 xp4 = *reinterpret_cast<float4*>(&x_re[row][c4 * 8 + nw * 4]);
                float s  = acc[mr * 4 + 0][rg] * xp4.x;
                s += acc[mr * 4 + 1][rg] * xp4.y;
                s += acc[mr * 4 + 2][rg] * xp4.z;
                s += acc[mr * 4 + 3][rg] * xp4.w;
                Sbuf[row][nw * 32 + col] = s * xq;
            }
        }

        // U1 term (reads x_re BEFORE the barrier)
        const int myrow = mw * 64 + lane;
        float u1dot = 0.f;
        #pragma unroll
        for (int s4 = 0; s4 < 4; ++s4) {
            const float4 xv = *reinterpret_cast<float4*>(&x_re[myrow][s4 * 4]);
            u1dot += xv.x * u1p[s4*4+0] + xv.y * u1p[s4*4+1] + xv.z * u1p[s4*4+2] + xv.w * u1p[s4*4+3];
        }
        const float w1v = W1[e * 128 + myrow];
        __syncthreads();   // Sbuf complete

        if (nw == 0) {
            float tot = u1dot * w1v;
            #pragma unroll
            for (int cc = 0; cc < 16; ++cc) {
                const float4 sv = *reinterpret_cast<float4*>(&Sbuf[myrow][cc * 4]);
                tot += sv.x + sv.y + sv.z + sv.w;
            }
            out[(size_t)tile * 128 + myrow] = tot;
        }
    }
}

extern "C" void kernel_launch(void* const* d_in, const int* in_sizes, int n_in,
                              void* d_out, int out_size, void* d_ws, size_t ws_size,
                              hipStream_t stream) {
    const float* x  = (const float*)d_in[0];
    const float* y  = (const float*)d_in[1];
    const float* U3 = (const float*)d_in[2];
    const float* U2 = (const float*)d_in[3];
    const float* U1 = (const float*)d_in[4];
    const float* W3 = (const float*)d_in[5];
    const float* W2 = (const float*)d_in[6];
    const float* W1 = (const float*)d_in[7];
    symcon_kernel<<<256, 256, 0, stream>>>(x, y, U3, U2, U1, W3, W2, W1, (float*)d_out);
}